// Round 7
// baseline (1159.719 us; speedup 1.0000x reference)
//
#include <hip/hip_runtime.h>
#include <math.h>

// Problem constants (reference: B,T,D=16,512,256; HS=512, D_A=64, R=8)
#define BB 16
#define TT 512
#define DD 256
#define HS 512
#define DA 64
#define RR 8
#define G4H 2048   // 4*HS

// -------- workspace layout (float offsets) --------
// s     :        0  (B*T*R =  65536)  <- k5's hbuf64 overlays this (dead by k3)
// e     :    65536
// inv   :   131072
// M     :   196608  (B*T*D   = 2097152)
// Pbuf  :  2293760  (B*8*D*R =  262144)  chunk partial sums for k3a/k3b

// fast transcendentals: v_exp_f32 + v_rcp_f32 (~1e-6 err << 1.5e-2 tol)
__device__ __forceinline__ float fast_sigmoid(float x) {
  return __builtin_amdgcn_rcpf(1.f + __expf(-x));
}
__device__ __forceinline__ float fast_tanh(float x) {
  const float xc = fmaxf(x, -30.f);           // avoid inf*0 NaN
  const float e = __expf(-2.f * xc);
  return (1.f - e) * __builtin_amdgcn_rcpf(1.f + e);
}

// ============================================================
// K1: s[b,t,r] = tanh(x[b,t,:] @ w1 + b1) @ w2 + b2
// (R7: libm tanhf -> fast_tanh; same approximation already used in k5,
//  error ~1e-6 << tolerance)
// ============================================================
__global__ __launch_bounds__(256) void k1_score(
    const float* __restrict__ x, const float* __restrict__ w1,
    const float* __restrict__ b1, const float* __restrict__ w2,
    const float* __restrict__ b2, float* __restrict__ s_out) {
  const int wave = threadIdx.x >> 6;
  const int lane = threadIdx.x & 63;
  for (int i = 0; i < 4; ++i) {
    const int bt = blockIdx.x * 16 + wave * 4 + i;  // grid=512 -> 8192 bt
    const float* xr = x + bt * DD;
    float acc = b1[lane];
    #pragma unroll 4
    for (int d = 0; d < DD; ++d)
      acc = fmaf(xr[d], w1[d * DA + lane], acc);   // w1 coalesced over lanes
    const float a = fast_tanh(acc);
    #pragma unroll
    for (int r = 0; r < RR; ++r) {
      float v = a * w2[lane * RR + r];
      for (int off = 32; off > 0; off >>= 1) v += __shfl_xor(v, off);
      if (lane == 0) s_out[bt * RR + r] = v + b2[r];
    }
  }
}

// ============================================================
// K2: per (b,r): m=max_t s; e=exp(s-m); den=inclusive prefix sum
// ============================================================
__global__ __launch_bounds__(512) void k2_prefix(
    const float* __restrict__ s_in, float* __restrict__ e_out,
    float* __restrict__ inv_out) {
  const int b = blockIdx.x >> 3, r = blockIdx.x & 7;
  const int t = threadIdx.x;
  __shared__ float red[TT];
  __shared__ float buf[2][TT];
  const float v = s_in[(b * TT + t) * RR + r];
  red[t] = v;
  __syncthreads();
  for (int off = 256; off >= 1; off >>= 1) {
    if (t < off) red[t] = fmaxf(red[t], red[t + off]);
    __syncthreads();
  }
  const float m = red[0];
  const float e = expf(v - m);
  int p = 0;
  buf[0][t] = e;
  __syncthreads();
  for (int off = 1; off < TT; off <<= 1) {
    const float add = (t >= off) ? buf[p][t - off] : 0.f;
    buf[1 - p][t] = buf[p][t] + add;
    __syncthreads();
    p ^= 1;
  }
  const float den = buf[p][t];
  e_out[(b * TT + t) * RR + r] = e;
  inv_out[(b * TT + t) * RR + r] = 1.0f / den;
}

// ============================================================
// K3 (R7: split into two passes for 8x T-parallelism; old k3 was 64
// blocks x 64 threads with a 512-long serial scan -- latency-bound).
// k3a: per (b, chunk of 64 t): P[r,d] = sum_{j in chunk} e[j,r]*x[j,d]
// k3b: per (b, chunk): offset c[r] = sum of earlier chunks' P, then
//      64-long in-chunk scan producing M rows. Same add order within
//      chunks; chunk-offset adds differ only in fp association (tol ok).
// ============================================================
__global__ __launch_bounds__(256) void k3a_partial(
    const float* __restrict__ x, const float* __restrict__ e_in,
    float* __restrict__ Pbuf) {
  const int b = blockIdx.x >> 3, ch = blockIdx.x & 7;
  const int d = threadIdx.x;
  __shared__ __align__(16) float el[64 * RR];
  if (threadIdx.x < 128)
    *(float4*)&el[threadIdx.x * 4] =
        *(const float4*)&e_in[(b * TT + ch * 64) * RR + threadIdx.x * 4];
  __syncthreads();
  float p0 = 0.f, p1 = 0.f, p2 = 0.f, p3 = 0.f;
  float p4 = 0.f, p5 = 0.f, p6 = 0.f, p7 = 0.f;
  for (int j = 0; j < 64; ++j) {
    const float xv = x[(b * TT + ch * 64 + j) * DD + d];
    const float4 e0 = *(const float4*)&el[j * RR];
    const float4 e1 = *(const float4*)&el[j * RR + 4];
    p0 = fmaf(e0.x, xv, p0); p1 = fmaf(e0.y, xv, p1);
    p2 = fmaf(e0.z, xv, p2); p3 = fmaf(e0.w, xv, p3);
    p4 = fmaf(e1.x, xv, p4); p5 = fmaf(e1.y, xv, p5);
    p6 = fmaf(e1.z, xv, p6); p7 = fmaf(e1.w, xv, p7);
  }
  float* pp = &Pbuf[((b * 8 + ch) * DD + d) * 8];
  float4 o0 = {p0, p1, p2, p3}, o1 = {p4, p5, p6, p7};
  *(float4*)pp = o0;
  *(float4*)(pp + 4) = o1;
}

__global__ __launch_bounds__(256) void k3b_scan(
    const float* __restrict__ x, const float* __restrict__ e_in,
    const float* __restrict__ inv_in, const float* __restrict__ Pbuf,
    float* __restrict__ Mout) {
  const int b = blockIdx.x >> 3, ch = blockIdx.x & 7;
  const int d = threadIdx.x;
  __shared__ __align__(16) float el[64 * RR];
  __shared__ __align__(16) float il[64 * RR];
  if (threadIdx.x < 128) {
    *(float4*)&el[threadIdx.x * 4] =
        *(const float4*)&e_in[(b * TT + ch * 64) * RR + threadIdx.x * 4];
    *(float4*)&il[threadIdx.x * 4] =
        *(const float4*)&inv_in[(b * TT + ch * 64) * RR + threadIdx.x * 4];
  }
  __syncthreads();
  float c0 = 0.f, c1 = 0.f, c2 = 0.f, c3 = 0.f;
  float c4 = 0.f, c5 = 0.f, c6 = 0.f, c7 = 0.f;
  for (int cp = 0; cp < ch; ++cp) {
    const float* pp = &Pbuf[((b * 8 + cp) * DD + d) * 8];
    const float4 a = *(const float4*)pp;
    const float4 bb = *(const float4*)(pp + 4);
    c0 += a.x; c1 += a.y; c2 += a.z; c3 += a.w;
    c4 += bb.x; c5 += bb.y; c6 += bb.z; c7 += bb.w;
  }
  for (int j = 0; j < 64; ++j) {
    const int t = ch * 64 + j;
    const float xv = x[(b * TT + t) * DD + d];
    const float4 e0 = *(const float4*)&el[j * RR];
    const float4 e1 = *(const float4*)&el[j * RR + 4];
    const float4 i0 = *(const float4*)&il[j * RR];
    const float4 i1 = *(const float4*)&il[j * RR + 4];
    c0 = fmaf(e0.x, xv, c0); c1 = fmaf(e0.y, xv, c1);
    c2 = fmaf(e0.z, xv, c2); c3 = fmaf(e0.w, xv, c3);
    c4 = fmaf(e1.x, xv, c4); c5 = fmaf(e1.y, xv, c5);
    c6 = fmaf(e1.z, xv, c6); c7 = fmaf(e1.w, xv, c7);
    float m = c0 * i0.x + c1 * i0.y + c2 * i0.z + c3 * i0.w;
    m += c4 * i1.x + c5 * i1.y + c6 * i1.z + c7 * i1.w;
    Mout[(b * TT + t) * DD + d] = m * 0.125f;
  }
}

#define FMA4(ACC, W4, HSC)                         \
  ACC.x = fmaf((W4).x, (HSC), ACC.x);              \
  ACC.y = fmaf((W4).y, (HSC), ACC.y);              \
  ACC.z = fmaf((W4).z, (HSC), ACC.z);              \
  ACC.w = fmaf((W4).w, (HSC), ACC.w);

#define HPOLL(Q) __hip_atomic_load((Q), __ATOMIC_RELAXED, __HIP_MEMORY_SCOPE_AGENT)

// ============================================================
// K5 v14 = v13 (943us; conflict-free W_ih verified 8.4M) + 4-DEEP
// ROTATING POLL, isolated this time. R6 verdict: conflict removal
// changed nothing -> k5 is exchange-RT-bound (~2400cy wait/step).
// The tight load->check loop samples once per MALL latency L
// (~600-900cy) -> discovery ~ prop + 1.5L. Four loads in flight
// (in-order vmcnt partial waits) sample every ~L/4 -> discovery ~
// prop + 1.1L, ~250-350cy/step less. This was R1's idea #2, poisoned
// there by the "+v" pin (whose per-iter AGPR copies explain all of
// R1's regression); protocol-identical, no new hazards.
// ============================================================
__global__ __launch_bounds__(512, 1) void k5_lstm(
    const float* __restrict__ Mrow, const float* __restrict__ whh,
    const float* __restrict__ wih, const float* __restrict__ bias,
    float* __restrict__ out, unsigned long long* hbuf) {
  const int s   = blockIdx.x & 15;       // unit-slice
  const int b   = blockIdx.x >> 4;       // batch = sync domain
  const int tid = threadIdx.x;           // 512 threads
  const int kq  = tid & 15;              // k-chunk: k in [kq*32, kq*32+32)
  const int cq  = tid >> 4;              // unit offset 0..31
  const int j0  = s * 32;
  const int unit = j0 + cq;

  __shared__ __align__(16) float Wl[32768];       // 128 KB (staging + W_ih)
  __shared__ __align__(16) float hl[2][576];      // parity; chunk*36+pos
  __shared__ __align__(16) float M_lds[2][320];   // stride-20 per 16 dims

  // ---- rounds 0-1: stage whh slice, gather wr into registers (= v7) ----
  float4 wr[32];
  for (int rnd = 0; rnd < 2; ++rnd) {
    for (int i = tid * 4; i < 256 * 128; i += 512 * 4) {
      const int k = i >> 7, c = i & 127;   // Wl[k][c], c = gate*32 + uo
      *(float4*)&Wl[i] =
          *(const float4*)&whh[(rnd * 256 + k) * G4H + (c >> 5) * HS + j0 + (c & 31)];
    }
    __syncthreads();
    if ((kq >> 3) == rnd) {
      const int kb = (kq & 7) * 32;
      #pragma unroll
      for (int kk = 0; kk < 32; ++kk) {
        const int base = (kb + kk) * 128 + cq;
        wr[kk].x = *(volatile const float*)&Wl[base];
        wr[kk].y = *(volatile const float*)&Wl[base + 32];
        wr[kk].z = *(volatile const float*)&Wl[base + 64];
        wr[kk].w = *(volatile const float*)&Wl[base + 96];
      }
    }
    __syncthreads();
  }

  // ---- round 2: stage W_ih slice, WAVE-CONTIGUOUS layout (v12) ----
  // word(wv,i,l) = wv*4096 + i*256 + l*4 holds the 4 gate columns of
  // unit j0 + (wv*4 + (l>>4)) at input dim (l&15)*16 + i. Reader wave
  // wv reads 1KB contiguous per (wv,i) -> conflict-free (verified:
  // SQ_LDS_BANK_CONFLICT 76.3M -> 8.4M).
  for (int m = tid * 4; m < 32768; m += 512 * 4) {
    const int wv = m >> 12;            // 0..7
    const int ii = (m >> 8) & 15;      // 0..15
    const int l  = (m >> 2) & 63;      // 0..63
    const int g_kq = l & 15, g_cq = wv * 4 + (l >> 4);
    const int row = g_kq * 16 + ii;    // input dim
    float4 w4;
    w4.x = wih[row * G4H + 0 * HS + j0 + g_cq];
    w4.y = wih[row * G4H + 1 * HS + j0 + g_cq];
    w4.z = wih[row * G4H + 2 * HS + j0 + g_cq];
    w4.w = wih[row * G4H + 3 * HS + j0 + g_cq];
    *(float4*)&Wl[m] = w4;
  }
  // M row 0 into parity buffer 0 (dim d lives at word (d>>4)*20 + (d&15))
  if (tid < 64)
    *(float4*)&M_lds[0][(tid >> 2) * 20 + (tid & 3) * 4] =
        *(const float4*)&Mrow[(long)b * TT * DD + tid * 4];
  // bias preload (epilogue lanes only)
  float bi = 0.f, bf = 0.f, bg = 0.f, bo = 0.f;
  if (kq == 0) {
    bi = bias[unit];          bf = bias[HS + unit];
    bg = bias[2 * HS + unit]; bo = bias[3 * HS + unit];
  }
  __syncthreads();

  float c_reg = 0.f;   // cell state (lives in lanes kq==0; unit j0+cq)

  for (int t = 0; t < TT; ++t) {
    const int par = t & 1;
    // prefetch M row t+1 (64 threads, one float4 each; lands during step)
    float4 mnext = {0.f, 0.f, 0.f, 0.f};
    if (tid < 64) {
      const int tn = (t + 1 < TT) ? t + 1 : t;   // clamp (last write unused)
      mnext = *(const float4*)&Mrow[((long)b * TT + tn) * DD + tid * 4];
    }
    // FMA-x: acc = W_ih partial over input dims [kq*16, kq*16+16).
    float4 acc = {0.f, 0.f, 0.f, 0.f};
    {
      const float* Lp = &Wl[(cq >> 2) * 4096 + ((cq & 3) * 16 + kq) * 4];
      const float* mp = &M_lds[par][kq * 20];
      #pragma unroll
      for (int i = 0; i < 16; ++i) {
        const float4 w4 = *(const float4*)(Lp + i * 256);
        const float mv = mp[i];
        FMA4(acc, w4, mv);
      }
    }
    // pin: keep FMA-x scheduled before the poll loop (cheap, once/step)
    asm volatile("" : "+v"(acc.x), "+v"(acc.y), "+v"(acc.z), "+v"(acc.w));
    if (t > 0) {
      // 4-deep rotating self-validating poll (tag >= t). In-order vmcnt
      // means checking q0 waits only vmcnt(3): sampling cadence ~L/4.
      const unsigned long long* hsrc =
          hbuf + (((t - 1) & 1) * BB + b) * HS + tid;
      const unsigned tt = (unsigned)t;
      unsigned long long q0, q1, q2, q3, pkt;
      q0 = HPOLL(hsrc); q1 = HPOLL(hsrc); q2 = HPOLL(hsrc); q3 = HPOLL(hsrc);
      for (;;) {
        if ((unsigned)(q0 >> 32) >= tt) { pkt = q0; break; }
        q0 = HPOLL(hsrc);
        if ((unsigned)(q1 >> 32) >= tt) { pkt = q1; break; }
        q1 = HPOLL(hsrc);
        if ((unsigned)(q2 >> 32) >= tt) { pkt = q2; break; }
        q2 = HPOLL(hsrc);
        if ((unsigned)(q3 >> 32) >= tt) { pkt = q3; break; }
        q3 = HPOLL(hsrc);
      }
      hl[par][(tid >> 5) * 36 + (tid & 31)] = __uint_as_float((unsigned)pkt);
    }
    // publish M row t+1 for next step (readers are past the barrier)
    if (tid < 64)
      *(float4*)&M_lds[par ^ 1][(tid >> 2) * 20 + (tid & 3) * 4] = mnext;
    __syncthreads();  // the ONE barrier: hl[par] + M_lds[par^1] complete
    if (t > 0) {
      const float* hb = &hl[par][kq * 36];
      #pragma unroll
      for (int i = 0; i < 8; ++i) {
        const float4 h4 = *(const float4*)(hb + i * 4);
        FMA4(acc, wr[i * 4 + 0], h4.x);
        FMA4(acc, wr[i * 4 + 1], h4.y);
        FMA4(acc, wr[i * 4 + 2], h4.z);
        FMA4(acc, wr[i * 4 + 3], h4.w);
      }
    }
    // butterfly over the 16 kq lanes (in-wave: group = 16 consecutive)
    #pragma unroll
    for (int off = 1; off <= 8; off <<= 1) {
      acc.x += __shfl_xor(acc.x, off); acc.y += __shfl_xor(acc.y, off);
      acc.z += __shfl_xor(acc.z, off); acc.w += __shfl_xor(acc.w, off);
    }
    // fused epilogue + publish: lane kq==0 has full (i,f,g,o) of unit
    if (kq == 0) {
      const float I = fast_sigmoid(acc.x + bi);
      const float F = fast_sigmoid(acc.y + bf);
      const float G = fast_tanh(acc.z + bg);
      const float O = fast_sigmoid(acc.w + bo);
      c_reg = F * c_reg + I * G;
      const float h = O * fast_tanh(c_reg);
      const unsigned long long pkt2 =
          ((unsigned long long)(unsigned)(t + 1) << 32) |
          (unsigned long long)__float_as_uint(h);
      __hip_atomic_store(&hbuf[((t & 1) * BB + b) * HS + unit], pkt2,
                         __ATOMIC_RELAXED, __HIP_MEMORY_SCOPE_AGENT);
      out[((long)b * TT + t) * HS + unit] = h;   // hidden_seq (post-publish)
      if (t == TT - 1) {
        out[(long)BB * TT * HS + b * HS + unit] = h;               // h_t
        out[(long)BB * TT * HS + BB * HS + b * HS + unit] = c_reg; // c_t
      }
    }
  }
}

// ============================================================
extern "C" void kernel_launch(void* const* d_in, const int* in_sizes, int n_in,
                              void* d_out, int out_size, void* d_ws,
                              size_t ws_size, hipStream_t stream) {
  const float* x    = (const float*)d_in[0];
  const float* w1   = (const float*)d_in[1];
  const float* b1   = (const float*)d_in[2];
  const float* w2   = (const float*)d_in[3];
  const float* b2   = (const float*)d_in[4];
  const float* wih  = (const float*)d_in[5];
  const float* whh  = (const float*)d_in[6];
  const float* bias = (const float*)d_in[7];
  float* out = (float*)d_out;

  float* ws = (float*)d_ws;
  float* s_buf  = ws;                    // 65536 floats; dead after k2
  float* e_buf  = ws + 65536;
  float* i_buf  = ws + 131072;
  float* M_buf  = ws + 196608;
  float* P_buf  = ws + 2293760;          // 262144 floats (old gates region)
  // hbuf64 overlays the s region (2*16*512 uint64 = 128 KB <= 256 KB)
  unsigned long long* hbuf64 = (unsigned long long*)ws;

  k1_score<<<512, 256, 0, stream>>>(x, w1, b1, w2, b2, s_buf);
  k2_prefix<<<BB * RR, 512, 0, stream>>>(s_buf, e_buf, i_buf);
  k3a_partial<<<BB * 8, 256, 0, stream>>>(x, e_buf, P_buf);
  k3b_scan<<<BB * 8, 256, 0, stream>>>(x, e_buf, i_buf, P_buf, M_buf);
  // zero the packet tags (ws re-poisoned 0xAA each call; 0xAAAAAAAA > any t
  // would instantly satisfy polls; and a stale same-step tag from the
  // previous rep would too). Stream-ordered after k2's s_buf reads.
  hipMemsetAsync(hbuf64, 0, 2 * BB * HS * sizeof(unsigned long long), stream);
  k5_lstm<<<256, 512, 0, stream>>>(M_buf, whh, wih, bias, out, hbuf64);
}

// Round 8
// 1048.945 us; speedup vs baseline: 1.1056x; 1.1056x over previous
//
#include <hip/hip_runtime.h>
#include <math.h>

// Problem constants (reference: B,T,D=16,512,256; HS=512, D_A=64, R=8)
#define BB 16
#define TT 512
#define DD 256
#define HS 512
#define DA 64
#define RR 8
#define G4H 2048   // 4*HS

// -------- workspace layout (float offsets) --------
// s     :        0  (B*T*R =  65536)  <- k5's hbuf64 overlays this (dead by k3)
// e     :    65536
// inv   :   131072
// M     :   196608  (B*T*D   = 2097152)
// Pbuf  :  2293760  (B*8*D*R =  262144)  chunk partial sums for k3a/k3b

// fast transcendentals: v_exp_f32 + v_rcp_f32 (~1e-6 err << 1.5e-2 tol)
__device__ __forceinline__ float fast_sigmoid(float x) {
  return __builtin_amdgcn_rcpf(1.f + __expf(-x));
}
__device__ __forceinline__ float fast_tanh(float x) {
  const float xc = fmaxf(x, -30.f);           // avoid inf*0 NaN
  const float e = __expf(-2.f * xc);
  return (1.f - e) * __builtin_amdgcn_rcpf(1.f + e);
}

// ============================================================
// K1: s[b,t,r] = tanh(x[b,t,:] @ w1 + b1) @ w2 + b2
// ============================================================
__global__ __launch_bounds__(256) void k1_score(
    const float* __restrict__ x, const float* __restrict__ w1,
    const float* __restrict__ b1, const float* __restrict__ w2,
    const float* __restrict__ b2, float* __restrict__ s_out) {
  const int wave = threadIdx.x >> 6;
  const int lane = threadIdx.x & 63;
  for (int i = 0; i < 4; ++i) {
    const int bt = blockIdx.x * 16 + wave * 4 + i;  // grid=512 -> 8192 bt
    const float* xr = x + bt * DD;
    float acc = b1[lane];
    #pragma unroll 4
    for (int d = 0; d < DD; ++d)
      acc = fmaf(xr[d], w1[d * DA + lane], acc);   // w1 coalesced over lanes
    const float a = fast_tanh(acc);
    #pragma unroll
    for (int r = 0; r < RR; ++r) {
      float v = a * w2[lane * RR + r];
      for (int off = 32; off > 0; off >>= 1) v += __shfl_xor(v, off);
      if (lane == 0) s_out[bt * RR + r] = v + b2[r];
    }
  }
}

// ============================================================
// K2: per (b,r): m=max_t s; e=exp(s-m); den=inclusive prefix sum
// ============================================================
__global__ __launch_bounds__(512) void k2_prefix(
    const float* __restrict__ s_in, float* __restrict__ e_out,
    float* __restrict__ inv_out) {
  const int b = blockIdx.x >> 3, r = blockIdx.x & 7;
  const int t = threadIdx.x;
  __shared__ float red[TT];
  __shared__ float buf[2][TT];
  const float v = s_in[(b * TT + t) * RR + r];
  red[t] = v;
  __syncthreads();
  for (int off = 256; off >= 1; off >>= 1) {
    if (t < off) red[t] = fmaxf(red[t], red[t + off]);
    __syncthreads();
  }
  const float m = red[0];
  const float e = expf(v - m);
  int p = 0;
  buf[0][t] = e;
  __syncthreads();
  for (int off = 1; off < TT; off <<= 1) {
    const float add = (t >= off) ? buf[p][t - off] : 0.f;
    buf[1 - p][t] = buf[p][t] + add;
    __syncthreads();
    p ^= 1;
  }
  const float den = buf[p][t];
  e_out[(b * TT + t) * RR + r] = e;
  inv_out[(b * TT + t) * RR + r] = 1.0f / den;
}

// ============================================================
// K3 split (R7, verified win): k3a per-chunk partials, k3b offset+scan.
// ============================================================
__global__ __launch_bounds__(256) void k3a_partial(
    const float* __restrict__ x, const float* __restrict__ e_in,
    float* __restrict__ Pbuf) {
  const int b = blockIdx.x >> 3, ch = blockIdx.x & 7;
  const int d = threadIdx.x;
  __shared__ __align__(16) float el[64 * RR];
  if (threadIdx.x < 128)
    *(float4*)&el[threadIdx.x * 4] =
        *(const float4*)&e_in[(b * TT + ch * 64) * RR + threadIdx.x * 4];
  __syncthreads();
  float p0 = 0.f, p1 = 0.f, p2 = 0.f, p3 = 0.f;
  float p4 = 0.f, p5 = 0.f, p6 = 0.f, p7 = 0.f;
  for (int j = 0; j < 64; ++j) {
    const float xv = x[(b * TT + ch * 64 + j) * DD + d];
    const float4 e0 = *(const float4*)&el[j * RR];
    const float4 e1 = *(const float4*)&el[j * RR + 4];
    p0 = fmaf(e0.x, xv, p0); p1 = fmaf(e0.y, xv, p1);
    p2 = fmaf(e0.z, xv, p2); p3 = fmaf(e0.w, xv, p3);
    p4 = fmaf(e1.x, xv, p4); p5 = fmaf(e1.y, xv, p5);
    p6 = fmaf(e1.z, xv, p6); p7 = fmaf(e1.w, xv, p7);
  }
  float* pp = &Pbuf[((b * 8 + ch) * DD + d) * 8];
  float4 o0 = {p0, p1, p2, p3}, o1 = {p4, p5, p6, p7};
  *(float4*)pp = o0;
  *(float4*)(pp + 4) = o1;
}

__global__ __launch_bounds__(256) void k3b_scan(
    const float* __restrict__ x, const float* __restrict__ e_in,
    const float* __restrict__ inv_in, const float* __restrict__ Pbuf,
    float* __restrict__ Mout) {
  const int b = blockIdx.x >> 3, ch = blockIdx.x & 7;
  const int d = threadIdx.x;
  __shared__ __align__(16) float el[64 * RR];
  __shared__ __align__(16) float il[64 * RR];
  if (threadIdx.x < 128) {
    *(float4*)&el[threadIdx.x * 4] =
        *(const float4*)&e_in[(b * TT + ch * 64) * RR + threadIdx.x * 4];
    *(float4*)&il[threadIdx.x * 4] =
        *(const float4*)&inv_in[(b * TT + ch * 64) * RR + threadIdx.x * 4];
  }
  __syncthreads();
  float c0 = 0.f, c1 = 0.f, c2 = 0.f, c3 = 0.f;
  float c4 = 0.f, c5 = 0.f, c6 = 0.f, c7 = 0.f;
  for (int cp = 0; cp < ch; ++cp) {
    const float* pp = &Pbuf[((b * 8 + cp) * DD + d) * 8];
    const float4 a = *(const float4*)pp;
    const float4 bb = *(const float4*)(pp + 4);
    c0 += a.x; c1 += a.y; c2 += a.z; c3 += a.w;
    c4 += bb.x; c5 += bb.y; c6 += bb.z; c7 += bb.w;
  }
  for (int j = 0; j < 64; ++j) {
    const int t = ch * 64 + j;
    const float xv = x[(b * TT + t) * DD + d];
    const float4 e0 = *(const float4*)&el[j * RR];
    const float4 e1 = *(const float4*)&el[j * RR + 4];
    const float4 i0 = *(const float4*)&il[j * RR];
    const float4 i1 = *(const float4*)&il[j * RR + 4];
    c0 = fmaf(e0.x, xv, c0); c1 = fmaf(e0.y, xv, c1);
    c2 = fmaf(e0.z, xv, c2); c3 = fmaf(e0.w, xv, c3);
    c4 = fmaf(e1.x, xv, c4); c5 = fmaf(e1.y, xv, c5);
    c6 = fmaf(e1.z, xv, c6); c7 = fmaf(e1.w, xv, c7);
    float m = c0 * i0.x + c1 * i0.y + c2 * i0.z + c3 * i0.w;
    m += c4 * i1.x + c5 * i1.y + c6 * i1.z + c7 * i1.w;
    Mout[(b * TT + t) * DD + d] = m * 0.125f;
  }
}

#define FMA4(ACC, W4, HSC)                         \
  ACC.x = fmaf((W4).x, (HSC), ACC.x);              \
  ACC.y = fmaf((W4).y, (HSC), ACC.y);              \
  ACC.z = fmaf((W4).z, (HSC), ACC.z);              \
  ACC.w = fmaf((W4).w, (HSC), ACC.w);

#define HPOLL(Q) __hip_atomic_load((Q), __ATOMIC_RELAXED, __HIP_MEMORY_SCOPE_AGENT)

// ============================================================
// K5 v15 = v13 EXACTLY (943us measured: k4-fused, conflict-free W_ih,
// TIGHT poll). R7 post-mortem: 4-deep rotating poll regressed in
// isolation too (943->1056; VALUBusy 45.5->41) -- all four loads share
// one vmcnt counter, so each check conservatively drains and costs a
// full RT while cycling through up to 4 stale slots: discovery ~4L,
// not ~1.1L. Poll-cadence hypothesis family CLOSED (2 failures);
// cache-scope family CLOSED (2 failures); LDS conflicts: no effect on
// the chain. The tight load->check loop is the measured optimum.
// Exchange protocol: v7, proven. tag >= t self-validating packets,
// parity slots, ONE barrier/step. memset is load-bearing (stale
// same-step tags from the previous rep would otherwise be accepted).
// ============================================================
__global__ __launch_bounds__(512, 1) void k5_lstm(
    const float* __restrict__ Mrow, const float* __restrict__ whh,
    const float* __restrict__ wih, const float* __restrict__ bias,
    float* __restrict__ out, unsigned long long* hbuf) {
  const int s   = blockIdx.x & 15;       // unit-slice
  const int b   = blockIdx.x >> 4;       // batch = sync domain
  const int tid = threadIdx.x;           // 512 threads
  const int kq  = tid & 15;              // k-chunk: k in [kq*32, kq*32+32)
  const int cq  = tid >> 4;              // unit offset 0..31
  const int j0  = s * 32;
  const int unit = j0 + cq;

  __shared__ __align__(16) float Wl[32768];       // 128 KB (staging + W_ih)
  __shared__ __align__(16) float hl[2][576];      // parity; chunk*36+pos
  __shared__ __align__(16) float M_lds[2][320];   // stride-20 per 16 dims

  // ---- rounds 0-1: stage whh slice, gather wr into registers (= v7) ----
  float4 wr[32];
  for (int rnd = 0; rnd < 2; ++rnd) {
    for (int i = tid * 4; i < 256 * 128; i += 512 * 4) {
      const int k = i >> 7, c = i & 127;   // Wl[k][c], c = gate*32 + uo
      *(float4*)&Wl[i] =
          *(const float4*)&whh[(rnd * 256 + k) * G4H + (c >> 5) * HS + j0 + (c & 31)];
    }
    __syncthreads();
    if ((kq >> 3) == rnd) {
      const int kb = (kq & 7) * 32;
      #pragma unroll
      for (int kk = 0; kk < 32; ++kk) {
        const int base = (kb + kk) * 128 + cq;
        wr[kk].x = *(volatile const float*)&Wl[base];
        wr[kk].y = *(volatile const float*)&Wl[base + 32];
        wr[kk].z = *(volatile const float*)&Wl[base + 64];
        wr[kk].w = *(volatile const float*)&Wl[base + 96];
      }
    }
    __syncthreads();
  }

  // ---- round 2: stage W_ih slice, WAVE-CONTIGUOUS layout ----
  // word(wv,i,l) = wv*4096 + i*256 + l*4 holds the 4 gate columns of
  // unit j0 + (wv*4 + (l>>4)) at input dim (l&15)*16 + i. Reader wave
  // wv reads 1KB contiguous per (wv,i) -> conflict-free (verified:
  // SQ_LDS_BANK_CONFLICT 76.3M -> 8.4M).
  for (int m = tid * 4; m < 32768; m += 512 * 4) {
    const int wv = m >> 12;            // 0..7
    const int ii = (m >> 8) & 15;      // 0..15
    const int l  = (m >> 2) & 63;      // 0..63
    const int g_kq = l & 15, g_cq = wv * 4 + (l >> 4);
    const int row = g_kq * 16 + ii;    // input dim
    float4 w4;
    w4.x = wih[row * G4H + 0 * HS + j0 + g_cq];
    w4.y = wih[row * G4H + 1 * HS + j0 + g_cq];
    w4.z = wih[row * G4H + 2 * HS + j0 + g_cq];
    w4.w = wih[row * G4H + 3 * HS + j0 + g_cq];
    *(float4*)&Wl[m] = w4;
  }
  // M row 0 into parity buffer 0 (dim d lives at word (d>>4)*20 + (d&15))
  if (tid < 64)
    *(float4*)&M_lds[0][(tid >> 2) * 20 + (tid & 3) * 4] =
        *(const float4*)&Mrow[(long)b * TT * DD + tid * 4];
  // bias preload (epilogue lanes only)
  float bi = 0.f, bf = 0.f, bg = 0.f, bo = 0.f;
  if (kq == 0) {
    bi = bias[unit];          bf = bias[HS + unit];
    bg = bias[2 * HS + unit]; bo = bias[3 * HS + unit];
  }
  __syncthreads();

  float c_reg = 0.f;   // cell state (lives in lanes kq==0; unit j0+cq)

  for (int t = 0; t < TT; ++t) {
    const int par = t & 1;
    // prefetch M row t+1 (64 threads, one float4 each; lands during step)
    float4 mnext = {0.f, 0.f, 0.f, 0.f};
    if (tid < 64) {
      const int tn = (t + 1 < TT) ? t + 1 : t;   // clamp (last write unused)
      mnext = *(const float4*)&Mrow[((long)b * TT + tn) * DD + tid * 4];
    }
    // FMA-x: acc = W_ih partial over input dims [kq*16, kq*16+16).
    float4 acc = {0.f, 0.f, 0.f, 0.f};
    {
      const float* Lp = &Wl[(cq >> 2) * 4096 + ((cq & 3) * 16 + kq) * 4];
      const float* mp = &M_lds[par][kq * 20];
      #pragma unroll
      for (int i = 0; i < 16; ++i) {
        const float4 w4 = *(const float4*)(Lp + i * 256);
        const float mv = mp[i];
        FMA4(acc, w4, mv);
      }
    }
    // pin: keep FMA-x scheduled before the poll loop (cheap, once/step)
    asm volatile("" : "+v"(acc.x), "+v"(acc.y), "+v"(acc.z), "+v"(acc.w));
    if (t > 0) {
      // self-validating TIGHT poll of my own unit's packet (tag >= t).
      const unsigned long long* hsrc =
          hbuf + (((t - 1) & 1) * BB + b) * HS + tid;
      unsigned long long pkt;
      do { pkt = HPOLL(hsrc); } while ((unsigned)(pkt >> 32) < (unsigned)t);
      hl[par][(tid >> 5) * 36 + (tid & 31)] = __uint_as_float((unsigned)pkt);
    }
    // publish M row t+1 for next step (readers are past the barrier)
    if (tid < 64)
      *(float4*)&M_lds[par ^ 1][(tid >> 2) * 20 + (tid & 3) * 4] = mnext;
    __syncthreads();  // the ONE barrier: hl[par] + M_lds[par^1] complete
    if (t > 0) {
      const float* hb = &hl[par][kq * 36];
      #pragma unroll
      for (int i = 0; i < 8; ++i) {
        const float4 h4 = *(const float4*)(hb + i * 4);
        FMA4(acc, wr[i * 4 + 0], h4.x);
        FMA4(acc, wr[i * 4 + 1], h4.y);
        FMA4(acc, wr[i * 4 + 2], h4.z);
        FMA4(acc, wr[i * 4 + 3], h4.w);
      }
    }
    // butterfly over the 16 kq lanes (in-wave: group = 16 consecutive)
    #pragma unroll
    for (int off = 1; off <= 8; off <<= 1) {
      acc.x += __shfl_xor(acc.x, off); acc.y += __shfl_xor(acc.y, off);
      acc.z += __shfl_xor(acc.z, off); acc.w += __shfl_xor(acc.w, off);
    }
    // fused epilogue + publish: lane kq==0 has full (i,f,g,o) of unit
    if (kq == 0) {
      const float I = fast_sigmoid(acc.x + bi);
      const float F = fast_sigmoid(acc.y + bf);
      const float G = fast_tanh(acc.z + bg);
      const float O = fast_sigmoid(acc.w + bo);
      c_reg = F * c_reg + I * G;
      const float h = O * fast_tanh(c_reg);
      const unsigned long long pkt2 =
          ((unsigned long long)(unsigned)(t + 1) << 32) |
          (unsigned long long)__float_as_uint(h);
      __hip_atomic_store(&hbuf[((t & 1) * BB + b) * HS + unit], pkt2,
                         __ATOMIC_RELAXED, __HIP_MEMORY_SCOPE_AGENT);
      out[((long)b * TT + t) * HS + unit] = h;   // hidden_seq (post-publish)
      if (t == TT - 1) {
        out[(long)BB * TT * HS + b * HS + unit] = h;               // h_t
        out[(long)BB * TT * HS + BB * HS + b * HS + unit] = c_reg; // c_t
      }
    }
  }
}

// ============================================================
extern "C" void kernel_launch(void* const* d_in, const int* in_sizes, int n_in,
                              void* d_out, int out_size, void* d_ws,
                              size_t ws_size, hipStream_t stream) {
  const float* x    = (const float*)d_in[0];
  const float* w1   = (const float*)d_in[1];
  const float* b1   = (const float*)d_in[2];
  const float* w2   = (const float*)d_in[3];
  const float* b2   = (const float*)d_in[4];
  const float* wih  = (const float*)d_in[5];
  const float* whh  = (const float*)d_in[6];
  const float* bias = (const float*)d_in[7];
  float* out = (float*)d_out;

  float* ws = (float*)d_ws;
  float* s_buf  = ws;                    // 65536 floats; dead after k2
  float* e_buf  = ws + 65536;
  float* i_buf  = ws + 131072;
  float* M_buf  = ws + 196608;
  float* P_buf  = ws + 2293760;          // 262144 floats (old gates region)
  // hbuf64 overlays the s region (2*16*512 uint64 = 128 KB <= 256 KB)
  unsigned long long* hbuf64 = (unsigned long long*)ws;

  k1_score<<<512, 256, 0, stream>>>(x, w1, b1, w2, b2, s_buf);
  k2_prefix<<<BB * RR, 512, 0, stream>>>(s_buf, e_buf, i_buf);
  k3a_partial<<<BB * 8, 256, 0, stream>>>(x, e_buf, P_buf);
  k3b_scan<<<BB * 8, 256, 0, stream>>>(x, e_buf, i_buf, P_buf, M_buf);
  // zero the packet tags (ws re-poisoned 0xAA each call; 0xAAAAAAAA > any t
  // would instantly satisfy polls; and a stale same-step tag from the
  // previous rep would too). Stream-ordered after k2's s_buf reads.
  hipMemsetAsync(hbuf64, 0, 2 * BB * HS * sizeof(unsigned long long), stream);
  k5_lstm<<<256, 512, 0, stream>>>(M_buf, whh, wih, bias, out, hbuf64);
}

// Round 9
// 1041.504 us; speedup vs baseline: 1.1135x; 1.0071x over previous
//
#include <hip/hip_runtime.h>
#include <math.h>

// Problem constants (reference: B,T,D=16,512,256; HS=512, D_A=64, R=8)
#define BB 16
#define TT 512
#define DD 256
#define HS 512
#define DA 64
#define RR 8
#define G4H 2048   // 4*HS

// -------- workspace layout (float offsets) --------
// s     :        0  (B*T*R =  65536)  <- k5's hbuf64 overlays this (dead by k3)
// e     :    65536
// inv   :   131072
// M     :   196608  (B*T*D   = 2097152)
// Pbuf  :  2293760  (B*8*D*R =  262144)  chunk partial sums for k3a/k3b

// fast transcendentals: v_exp_f32 + v_rcp_f32 (~1e-6 err << 1.5e-2 tol)
__device__ __forceinline__ float fast_sigmoid(float x) {
  return __builtin_amdgcn_rcpf(1.f + __expf(-x));
}
__device__ __forceinline__ float fast_tanh(float x) {
  const float xc = fmaxf(x, -30.f);           // avoid inf*0 NaN
  const float e = __expf(-2.f * xc);
  return (1.f - e) * __builtin_amdgcn_rcpf(1.f + e);
}

// ============================================================
// K1: s[b,t,r] = tanh(x[b,t,:] @ w1 + b1) @ w2 + b2
// ============================================================
__global__ __launch_bounds__(256) void k1_score(
    const float* __restrict__ x, const float* __restrict__ w1,
    const float* __restrict__ b1, const float* __restrict__ w2,
    const float* __restrict__ b2, float* __restrict__ s_out) {
  const int wave = threadIdx.x >> 6;
  const int lane = threadIdx.x & 63;
  for (int i = 0; i < 4; ++i) {
    const int bt = blockIdx.x * 16 + wave * 4 + i;  // grid=512 -> 8192 bt
    const float* xr = x + bt * DD;
    float acc = b1[lane];
    #pragma unroll 4
    for (int d = 0; d < DD; ++d)
      acc = fmaf(xr[d], w1[d * DA + lane], acc);   // w1 coalesced over lanes
    const float a = fast_tanh(acc);
    #pragma unroll
    for (int r = 0; r < RR; ++r) {
      float v = a * w2[lane * RR + r];
      for (int off = 32; off > 0; off >>= 1) v += __shfl_xor(v, off);
      if (lane == 0) s_out[bt * RR + r] = v + b2[r];
    }
  }
}

// ============================================================
// K2 (R9: wave-scan rewrite): per (b,r): m=max_t s; e=exp(s-m);
// den=inclusive prefix sum. Old version: 19 barriered LDS phases.
// New: wave shfl max-reduce + shfl_up inclusive scan + 8-entry
// cross-wave fixup -> 2 barriers. expf -> __expf (v_exp_f32; err
// ~1e-7 rel, 15x headroom vs tol; same approx family as k5 gates).
// ============================================================
__global__ __launch_bounds__(512) void k2_prefix(
    const float* __restrict__ s_in, float* __restrict__ e_out,
    float* __restrict__ inv_out) {
  const int b = blockIdx.x >> 3, r = blockIdx.x & 7;
  const int t = threadIdx.x;           // 0..511 (= TT threads)
  const int lane = t & 63, wv = t >> 6;  // 8 waves
  __shared__ float wmax[8];
  __shared__ float wsum[8];
  const float v = s_in[(b * TT + t) * RR + r];
  // global max: wave shfl reduce, then 8-entry combine
  float m = v;
  #pragma unroll
  for (int off = 1; off <= 32; off <<= 1) m = fmaxf(m, __shfl_xor(m, off));
  if (lane == 0) wmax[wv] = m;
  __syncthreads();
  float mm = wmax[0];
  #pragma unroll
  for (int i = 1; i < 8; ++i) mm = fmaxf(mm, wmax[i]);
  const float e = __expf(v - mm);
  // inclusive prefix sum: wave shfl_up scan, then wave-offset fixup
  float ps = e;
  #pragma unroll
  for (int off = 1; off <= 32; off <<= 1) {
    const float nb = __shfl_up(ps, off);
    if (lane >= off) ps += nb;
  }
  if (lane == 63) wsum[wv] = ps;
  __syncthreads();
  float offacc = 0.f;
  for (int i = 0; i < 8; ++i) offacc += (i < wv) ? wsum[i] : 0.f;
  const float den = ps + offacc;
  e_out[(b * TT + t) * RR + r] = e;
  inv_out[(b * TT + t) * RR + r] = 1.0f / den;
}

// ============================================================
// K3 split (R7, verified win): k3a per-chunk partials, k3b offset+scan.
// R9: k3a also zeroes hbuf (replaces the hipMemsetAsync dispatch).
// Safe: hbuf overlays the s region, dead after k2; k3a is stream-
// ordered after k2 and before k5, so k5 sees zeroed tags exactly as
// with the memset. The zero is load-bearing (ws re-poisoned 0xAA each
// call; 0xAAAAAAAA > any t would instantly satisfy polls, and stale
// same-step tags from the previous rep would be accepted).
// ============================================================
__global__ __launch_bounds__(256) void k3a_partial(
    const float* __restrict__ x, const float* __restrict__ e_in,
    float* __restrict__ Pbuf, unsigned long long* __restrict__ hbuf) {
  // zero packet tags: first 64 blocks x 256 threads cover 16384 u64
  const int g = blockIdx.x * 256 + threadIdx.x;
  if (g < 2 * BB * HS) hbuf[g] = 0ULL;
  const int b = blockIdx.x >> 3, ch = blockIdx.x & 7;
  const int d = threadIdx.x;
  __shared__ __align__(16) float el[64 * RR];
  if (threadIdx.x < 128)
    *(float4*)&el[threadIdx.x * 4] =
        *(const float4*)&e_in[(b * TT + ch * 64) * RR + threadIdx.x * 4];
  __syncthreads();
  float p0 = 0.f, p1 = 0.f, p2 = 0.f, p3 = 0.f;
  float p4 = 0.f, p5 = 0.f, p6 = 0.f, p7 = 0.f;
  for (int j = 0; j < 64; ++j) {
    const float xv = x[(b * TT + ch * 64 + j) * DD + d];
    const float4 e0 = *(const float4*)&el[j * RR];
    const float4 e1 = *(const float4*)&el[j * RR + 4];
    p0 = fmaf(e0.x, xv, p0); p1 = fmaf(e0.y, xv, p1);
    p2 = fmaf(e0.z, xv, p2); p3 = fmaf(e0.w, xv, p3);
    p4 = fmaf(e1.x, xv, p4); p5 = fmaf(e1.y, xv, p5);
    p6 = fmaf(e1.z, xv, p6); p7 = fmaf(e1.w, xv, p7);
  }
  float* pp = &Pbuf[((b * 8 + ch) * DD + d) * 8];
  float4 o0 = {p0, p1, p2, p3}, o1 = {p4, p5, p6, p7};
  *(float4*)pp = o0;
  *(float4*)(pp + 4) = o1;
}

__global__ __launch_bounds__(256) void k3b_scan(
    const float* __restrict__ x, const float* __restrict__ e_in,
    const float* __restrict__ inv_in, const float* __restrict__ Pbuf,
    float* __restrict__ Mout) {
  const int b = blockIdx.x >> 3, ch = blockIdx.x & 7;
  const int d = threadIdx.x;
  __shared__ __align__(16) float el[64 * RR];
  __shared__ __align__(16) float il[64 * RR];
  if (threadIdx.x < 128) {
    *(float4*)&el[threadIdx.x * 4] =
        *(const float4*)&e_in[(b * TT + ch * 64) * RR + threadIdx.x * 4];
    *(float4*)&il[threadIdx.x * 4] =
        *(const float4*)&inv_in[(b * TT + ch * 64) * RR + threadIdx.x * 4];
  }
  __syncthreads();
  float c0 = 0.f, c1 = 0.f, c2 = 0.f, c3 = 0.f;
  float c4 = 0.f, c5 = 0.f, c6 = 0.f, c7 = 0.f;
  for (int cp = 0; cp < ch; ++cp) {
    const float* pp = &Pbuf[((b * 8 + cp) * DD + d) * 8];
    const float4 a = *(const float4*)pp;
    const float4 bb = *(const float4*)(pp + 4);
    c0 += a.x; c1 += a.y; c2 += a.z; c3 += a.w;
    c4 += bb.x; c5 += bb.y; c6 += bb.z; c7 += bb.w;
  }
  for (int j = 0; j < 64; ++j) {
    const int t = ch * 64 + j;
    const float xv = x[(b * TT + t) * DD + d];
    const float4 e0 = *(const float4*)&el[j * RR];
    const float4 e1 = *(const float4*)&el[j * RR + 4];
    const float4 i0 = *(const float4*)&il[j * RR];
    const float4 i1 = *(const float4*)&il[j * RR + 4];
    c0 = fmaf(e0.x, xv, c0); c1 = fmaf(e0.y, xv, c1);
    c2 = fmaf(e0.z, xv, c2); c3 = fmaf(e0.w, xv, c3);
    c4 = fmaf(e1.x, xv, c4); c5 = fmaf(e1.y, xv, c5);
    c6 = fmaf(e1.z, xv, c6); c7 = fmaf(e1.w, xv, c7);
    float m = c0 * i0.x + c1 * i0.y + c2 * i0.z + c3 * i0.w;
    m += c4 * i1.x + c5 * i1.y + c6 * i1.z + c7 * i1.w;
    Mout[(b * TT + t) * DD + d] = m * 0.125f;
  }
}

#define FMA4(ACC, W4, HSC)                         \
  ACC.x = fmaf((W4).x, (HSC), ACC.x);              \
  ACC.y = fmaf((W4).y, (HSC), ACC.y);              \
  ACC.z = fmaf((W4).z, (HSC), ACC.z);              \
  ACC.w = fmaf((W4).w, (HSC), ACC.w);

#define HPOLL(Q) __hip_atomic_load((Q), __ATOMIC_RELAXED, __HIP_MEMORY_SCOPE_AGENT)

// ============================================================
// K5 v15 FROZEN (948us steady, measured twice). k4-fused, conflict-
// free W_ih (8.39M), tight poll. Closed families: cache-scope (x2),
// poll cadence (x2), LDS conflicts (no path effect). Exchange floor:
// ~2400cy/step fabric RT. NOTE: k5 must launch strictly after k3b --
// overlap would break block co-residency and can deadlock the polls.
// ============================================================
__global__ __launch_bounds__(512, 1) void k5_lstm(
    const float* __restrict__ Mrow, const float* __restrict__ whh,
    const float* __restrict__ wih, const float* __restrict__ bias,
    float* __restrict__ out, unsigned long long* hbuf) {
  const int s   = blockIdx.x & 15;       // unit-slice
  const int b   = blockIdx.x >> 4;       // batch = sync domain
  const int tid = threadIdx.x;           // 512 threads
  const int kq  = tid & 15;              // k-chunk: k in [kq*32, kq*32+32)
  const int cq  = tid >> 4;              // unit offset 0..31
  const int j0  = s * 32;
  const int unit = j0 + cq;

  __shared__ __align__(16) float Wl[32768];       // 128 KB (staging + W_ih)
  __shared__ __align__(16) float hl[2][576];      // parity; chunk*36+pos
  __shared__ __align__(16) float M_lds[2][320];   // stride-20 per 16 dims

  // ---- rounds 0-1: stage whh slice, gather wr into registers (= v7) ----
  float4 wr[32];
  for (int rnd = 0; rnd < 2; ++rnd) {
    for (int i = tid * 4; i < 256 * 128; i += 512 * 4) {
      const int k = i >> 7, c = i & 127;   // Wl[k][c], c = gate*32 + uo
      *(float4*)&Wl[i] =
          *(const float4*)&whh[(rnd * 256 + k) * G4H + (c >> 5) * HS + j0 + (c & 31)];
    }
    __syncthreads();
    if ((kq >> 3) == rnd) {
      const int kb = (kq & 7) * 32;
      #pragma unroll
      for (int kk = 0; kk < 32; ++kk) {
        const int base = (kb + kk) * 128 + cq;
        wr[kk].x = *(volatile const float*)&Wl[base];
        wr[kk].y = *(volatile const float*)&Wl[base + 32];
        wr[kk].z = *(volatile const float*)&Wl[base + 64];
        wr[kk].w = *(volatile const float*)&Wl[base + 96];
      }
    }
    __syncthreads();
  }

  // ---- round 2: stage W_ih slice, WAVE-CONTIGUOUS layout ----
  // word(wv,i,l) = wv*4096 + i*256 + l*4 holds the 4 gate columns of
  // unit j0 + (wv*4 + (l>>4)) at input dim (l&15)*16 + i. Reader wave
  // wv reads 1KB contiguous per (wv,i) -> conflict-free (verified:
  // SQ_LDS_BANK_CONFLICT 76.3M -> 8.4M).
  for (int m = tid * 4; m < 32768; m += 512 * 4) {
    const int wv = m >> 12;            // 0..7
    const int ii = (m >> 8) & 15;      // 0..15
    const int l  = (m >> 2) & 63;      // 0..63
    const int g_kq = l & 15, g_cq = wv * 4 + (l >> 4);
    const int row = g_kq * 16 + ii;    // input dim
    float4 w4;
    w4.x = wih[row * G4H + 0 * HS + j0 + g_cq];
    w4.y = wih[row * G4H + 1 * HS + j0 + g_cq];
    w4.z = wih[row * G4H + 2 * HS + j0 + g_cq];
    w4.w = wih[row * G4H + 3 * HS + j0 + g_cq];
    *(float4*)&Wl[m] = w4;
  }
  // M row 0 into parity buffer 0 (dim d lives at word (d>>4)*20 + (d&15))
  if (tid < 64)
    *(float4*)&M_lds[0][(tid >> 2) * 20 + (tid & 3) * 4] =
        *(const float4*)&Mrow[(long)b * TT * DD + tid * 4];
  // bias preload (epilogue lanes only)
  float bi = 0.f, bf = 0.f, bg = 0.f, bo = 0.f;
  if (kq == 0) {
    bi = bias[unit];          bf = bias[HS + unit];
    bg = bias[2 * HS + unit]; bo = bias[3 * HS + unit];
  }
  __syncthreads();

  float c_reg = 0.f;   // cell state (lives in lanes kq==0; unit j0+cq)

  for (int t = 0; t < TT; ++t) {
    const int par = t & 1;
    // prefetch M row t+1 (64 threads, one float4 each; lands during step)
    float4 mnext = {0.f, 0.f, 0.f, 0.f};
    if (tid < 64) {
      const int tn = (t + 1 < TT) ? t + 1 : t;   // clamp (last write unused)
      mnext = *(const float4*)&Mrow[((long)b * TT + tn) * DD + tid * 4];
    }
    // FMA-x: acc = W_ih partial over input dims [kq*16, kq*16+16).
    float4 acc = {0.f, 0.f, 0.f, 0.f};
    {
      const float* Lp = &Wl[(cq >> 2) * 4096 + ((cq & 3) * 16 + kq) * 4];
      const float* mp = &M_lds[par][kq * 20];
      #pragma unroll
      for (int i = 0; i < 16; ++i) {
        const float4 w4 = *(const float4*)(Lp + i * 256);
        const float mv = mp[i];
        FMA4(acc, w4, mv);
      }
    }
    // pin: keep FMA-x scheduled before the poll loop (cheap, once/step)
    asm volatile("" : "+v"(acc.x), "+v"(acc.y), "+v"(acc.z), "+v"(acc.w));
    if (t > 0) {
      // self-validating TIGHT poll of my own unit's packet (tag >= t).
      const unsigned long long* hsrc =
          hbuf + (((t - 1) & 1) * BB + b) * HS + tid;
      unsigned long long pkt;
      do { pkt = HPOLL(hsrc); } while ((unsigned)(pkt >> 32) < (unsigned)t);
      hl[par][(tid >> 5) * 36 + (tid & 31)] = __uint_as_float((unsigned)pkt);
    }
    // publish M row t+1 for next step (readers are past the barrier)
    if (tid < 64)
      *(float4*)&M_lds[par ^ 1][(tid >> 2) * 20 + (tid & 3) * 4] = mnext;
    __syncthreads();  // the ONE barrier: hl[par] + M_lds[par^1] complete
    if (t > 0) {
      const float* hb = &hl[par][kq * 36];
      #pragma unroll
      for (int i = 0; i < 8; ++i) {
        const float4 h4 = *(const float4*)(hb + i * 4);
        FMA4(acc, wr[i * 4 + 0], h4.x);
        FMA4(acc, wr[i * 4 + 1], h4.y);
        FMA4(acc, wr[i * 4 + 2], h4.z);
        FMA4(acc, wr[i * 4 + 3], h4.w);
      }
    }
    // butterfly over the 16 kq lanes (in-wave: group = 16 consecutive)
    #pragma unroll
    for (int off = 1; off <= 8; off <<= 1) {
      acc.x += __shfl_xor(acc.x, off); acc.y += __shfl_xor(acc.y, off);
      acc.z += __shfl_xor(acc.z, off); acc.w += __shfl_xor(acc.w, off);
    }
    // fused epilogue + publish: lane kq==0 has full (i,f,g,o) of unit
    if (kq == 0) {
      const float I = fast_sigmoid(acc.x + bi);
      const float F = fast_sigmoid(acc.y + bf);
      const float G = fast_tanh(acc.z + bg);
      const float O = fast_sigmoid(acc.w + bo);
      c_reg = F * c_reg + I * G;
      const float h = O * fast_tanh(c_reg);
      const unsigned long long pkt2 =
          ((unsigned long long)(unsigned)(t + 1) << 32) |
          (unsigned long long)__float_as_uint(h);
      __hip_atomic_store(&hbuf[((t & 1) * BB + b) * HS + unit], pkt2,
                         __ATOMIC_RELAXED, __HIP_MEMORY_SCOPE_AGENT);
      out[((long)b * TT + t) * HS + unit] = h;   // hidden_seq (post-publish)
      if (t == TT - 1) {
        out[(long)BB * TT * HS + b * HS + unit] = h;               // h_t
        out[(long)BB * TT * HS + BB * HS + b * HS + unit] = c_reg; // c_t
      }
    }
  }
}

// ============================================================
extern "C" void kernel_launch(void* const* d_in, const int* in_sizes, int n_in,
                              void* d_out, int out_size, void* d_ws,
                              size_t ws_size, hipStream_t stream) {
  const float* x    = (const float*)d_in[0];
  const float* w1   = (const float*)d_in[1];
  const float* b1   = (const float*)d_in[2];
  const float* w2   = (const float*)d_in[3];
  const float* b2   = (const float*)d_in[4];
  const float* wih  = (const float*)d_in[5];
  const float* whh  = (const float*)d_in[6];
  const float* bias = (const float*)d_in[7];
  float* out = (float*)d_out;

  float* ws = (float*)d_ws;
  float* s_buf  = ws;                    // 65536 floats; dead after k2
  float* e_buf  = ws + 65536;
  float* i_buf  = ws + 131072;
  float* M_buf  = ws + 196608;
  float* P_buf  = ws + 2293760;          // 262144 floats (old gates region)
  // hbuf64 overlays the s region (2*16*512 uint64 = 128 KB <= 256 KB);
  // zeroed inside k3a (stream-ordered after k2's s_buf reads, before k5).
  unsigned long long* hbuf64 = (unsigned long long*)ws;

  k1_score<<<512, 256, 0, stream>>>(x, w1, b1, w2, b2, s_buf);
  k2_prefix<<<BB * RR, 512, 0, stream>>>(s_buf, e_buf, i_buf);
  k3a_partial<<<BB * 8, 256, 0, stream>>>(x, e_buf, P_buf, hbuf64);
  k3b_scan<<<BB * 8, 256, 0, stream>>>(x, e_buf, i_buf, P_buf, M_buf);
  k5_lstm<<<256, 512, 0, stream>>>(M_buf, whh, wih, bias, out, hbuf64);
}